// Round 1
// baseline (359.469 us; speedup 1.0000x reference)
//
#include <hip/hip_runtime.h>
#include <hip/hip_bf16.h>
#include <stdint.h>

// Problem constants
#define B_   512
#define T_   87
#define C_   512
#define H_   8
#define D_   64
#define BT_  44544        // B_*T_
#define TP_  96           // padded T (6 x 16)
#define BH_  4096         // B_*H_

typedef __attribute__((ext_vector_type(4))) float f32x4;
typedef __attribute__((ext_vector_type(8))) __bf16 bf16x8;
typedef __attribute__((ext_vector_type(4))) unsigned short u16x4;

__device__ __forceinline__ void gl_lds16(const void* g, void* l) {
  __builtin_amdgcn_global_load_lds(
      (const __attribute__((address_space(1))) unsigned int*)g,
      (__attribute__((address_space(3))) unsigned int*)l, 16, 0, 0);
}

__device__ __forceinline__ int mod29(int x) {
  return x < 29 ? x : (x < 58 ? x - 29 : x - 58);
}

// ---------------- converts ----------------

__global__ void convert_x_kernel(const float* __restrict__ x,
                                 __hip_bfloat16* __restrict__ xb, int n4) {
  int stride = gridDim.x * blockDim.x;
  for (int i = blockIdx.x * blockDim.x + threadIdx.x; i < n4; i += stride) {
    f32x4 v = ((const f32x4*)x)[i];
    u16x4 o;
    o.x = __builtin_bit_cast(unsigned short, __float2bfloat16(v.x));
    o.y = __builtin_bit_cast(unsigned short, __float2bfloat16(v.y));
    o.z = __builtin_bit_cast(unsigned short, __float2bfloat16(v.z));
    o.w = __builtin_bit_cast(unsigned short, __float2bfloat16(v.w));
    ((u16x4*)xb)[i] = o;
  }
}

__global__ void convert_w_kernel(const float* __restrict__ Wq, const float* __restrict__ Wk,
                                 const float* __restrict__ Wv, const float* __restrict__ Wp,
                                 const float* __restrict__ bq, const float* __restrict__ bk,
                                 const float* __restrict__ bv,
                                 __hip_bfloat16* __restrict__ wqkv,
                                 __hip_bfloat16* __restrict__ wp,
                                 float* __restrict__ biasc) {
  const int NW = 262144;                 // 512*512
  const int total = 3 * NW + NW + 1536;
  int stride = gridDim.x * blockDim.x;
  for (int i = blockIdx.x * blockDim.x + threadIdx.x; i < total; i += stride) {
    if (i < 3 * NW) {
      float v = (i < NW) ? Wq[i] : (i < 2 * NW ? Wk[i - NW] : Wv[i - 2 * NW]);
      wqkv[i] = __float2bfloat16(v);
    } else if (i < 4 * NW) {
      wp[i - 3 * NW] = __float2bfloat16(Wp[i - 3 * NW]);
    } else {
      int j = i - 4 * NW;
      biasc[j] = (j < 512) ? bq[j] : (j < 1024 ? bk[j - 512] : bv[j - 1024]);
    }
  }
}

// zero the pad rows (t = 87..95) of q/k and pad cols of vt
__global__ void zero_pads_kernel(__hip_bfloat16* __restrict__ q_ws,
                                 __hip_bfloat16* __restrict__ k_ws,
                                 __hip_bfloat16* __restrict__ vt_ws) {
  const int per = BH_ * 576;  // 9*64 pad elems per (b,h)
  int stride = gridDim.x * blockDim.x;
  __hip_bfloat16 z = __float2bfloat16(0.f);
  for (int i = blockIdx.x * blockDim.x + threadIdx.x; i < 3 * per; i += stride) {
    if (i < per) {
      int bh = i / 576, rem = i - (i / 576) * 576;
      q_ws[(size_t)bh * 6144 + 5568 + rem] = z;
    } else if (i < 2 * per) {
      int j = i - per;
      int bh = j / 576, rem = j - (j / 576) * 576;
      k_ws[(size_t)bh * 6144 + 5568 + rem] = z;
    } else {
      int j = i - 2 * per;
      int bh = j / 576, rem = j - (j / 576) * 576;
      int d = rem / 9, o = rem - d * 9;
      vt_ws[(size_t)bh * 6144 + d * 96 + 87 + o] = z;
    }
  }
}

// ---------------- fused QKV GEMM ----------------
// A: xb [BT_,512] bf16 row-major; Bt: wqkv [1536,512] bf16 (y = x @ W^T)
// epilogue scatters to q/k [bh][96][64] and vt [bh][64][96]
__global__ __launch_bounds__(256) void gemm_qkv_kernel(
    const __hip_bfloat16* __restrict__ A, const __hip_bfloat16* __restrict__ Bt,
    const float* __restrict__ bias,
    __hip_bfloat16* __restrict__ q_ws, __hip_bfloat16* __restrict__ k_ws,
    __hip_bfloat16* __restrict__ vt_ws) {
  __shared__ __align__(16) __hip_bfloat16 As[128 * 64];
  __shared__ __align__(16) __hip_bfloat16 Bs[128 * 64];
  const int K = 512;
  int tid = threadIdx.x, lane = tid & 63, wave = tid >> 6;
  int tileN = blockIdx.x * 128;   // x fastest -> blocks sharing A panel adjacent
  int tileM = blockIdx.y * 128;
  int wr = wave >> 1, wc = wave & 1;
  int r16 = lane & 15, r4 = lane >> 4;
  int srow = lane >> 3, scol = (lane & 7) * 8;

  f32x4 acc[4][4] = {};

  for (int kt = 0; kt < 8; ++kt) {
    int k0 = kt * 64;
#pragma unroll
    for (int i = 0; i < 4; ++i) {
      int blkr = (i * 4 + wave) * 8;  // wave-uniform row block
      const __hip_bfloat16* gA = A + (size_t)(tileM + blkr + srow) * K + k0 + scol;
      const __hip_bfloat16* gB = Bt + (size_t)(tileN + blkr + srow) * K + k0 + scol;
      gl_lds16(gA, (char*)As + blkr * 128);
      gl_lds16(gB, (char*)Bs + blkr * 128);
    }
    __syncthreads();
#pragma unroll
    for (int kk = 0; kk < 2; ++kk) {
      bf16x8 af[4], bf[4];
#pragma unroll
      for (int mi = 0; mi < 4; ++mi)
        af[mi] = *(const bf16x8*)((const char*)As +
                                  (wr * 64 + mi * 16 + r16) * 128 + kk * 64 + r4 * 16);
#pragma unroll
      for (int ni = 0; ni < 4; ++ni)
        bf[ni] = *(const bf16x8*)((const char*)Bs +
                                  (wc * 64 + ni * 16 + r16) * 128 + kk * 64 + r4 * 16);
#pragma unroll
      for (int mi = 0; mi < 4; ++mi)
#pragma unroll
        for (int ni = 0; ni < 4; ++ni)
          acc[mi][ni] = __builtin_amdgcn_mfma_f32_16x16x32_bf16(af[mi], bf[ni],
                                                                acc[mi][ni], 0, 0, 0);
    }
    __syncthreads();
  }

  // epilogue: C/D layout col=lane&15, row=(lane>>4)*4+reg  [m89-verified]
#pragma unroll
  for (int mi = 0; mi < 4; ++mi) {
#pragma unroll
    for (int ni = 0; ni < 4; ++ni) {
      int gn = tileN + wc * 64 + ni * 16 + r16;
      float bv = bias[gn];
#pragma unroll
      for (int r = 0; r < 4; ++r) {
        int gm = tileM + wr * 64 + mi * 16 + r4 * 4 + r;
        float val = acc[mi][ni][r] + bv;
        __hip_bfloat16 hv = __float2bfloat16(val);
        int bb = gm / 87;
        int tt = gm - bb * 87;
        if (gn < 512) {
          int hh = gn >> 6, dd = gn & 63;
          q_ws[((size_t)(bb * 8 + hh) * 96 + tt) * 64 + dd] = hv;
        } else if (gn < 1024) {
          int n2 = gn - 512;
          int hh = n2 >> 6, dd = n2 & 63;
          k_ws[((size_t)(bb * 8 + hh) * 96 + tt) * 64 + dd] = hv;
        } else {
          int n2 = gn - 1024;
          int hh = n2 >> 6, dd = n2 & 63;
          vt_ws[((size_t)(bb * 8 + hh) * 64 + dd) * 96 + tt] = hv;
        }
      }
    }
  }
}

// ---------------- attention per (b,h) ----------------
__global__ __launch_bounds__(256) void attn_kernel(
    const __hip_bfloat16* __restrict__ q_ws, const __hip_bfloat16* __restrict__ k_ws,
    const __hip_bfloat16* __restrict__ vt_ws, __hip_bfloat16* __restrict__ y_ws) {
  __shared__ __align__(16) char smem[73728];
  __hip_bfloat16* Qs  = (__hip_bfloat16*)smem;             // [96][64] 12KB
  __hip_bfloat16* Ks  = (__hip_bfloat16*)(smem + 12288);   // [96][64] 12KB
  __hip_bfloat16* Vts = (__hip_bfloat16*)(smem + 24576);   // [64][96] 12KB
  float* Sb           = (float*)(smem + 36864);            // [96][96] fp32 36KB
  __hip_bfloat16* Pb  = (__hip_bfloat16*)smem;             // [96][96] aliases Qs+Ks

  int tid = threadIdx.x, lane = tid & 63, wave = tid >> 6;
  int bh = blockIdx.x, b = bh >> 3, h = bh & 7;
  int r16 = lane & 15, r4 = lane >> 4;

  {
    const bf16x8* gq = (const bf16x8*)(q_ws + (size_t)bh * 6144);
    const bf16x8* gk = (const bf16x8*)(k_ws + (size_t)bh * 6144);
    const bf16x8* gv = (const bf16x8*)(vt_ws + (size_t)bh * 6144);
    bf16x8* lq = (bf16x8*)Qs; bf16x8* lk = (bf16x8*)Ks; bf16x8* lv = (bf16x8*)Vts;
    for (int i = tid; i < 768; i += 256) { lq[i] = gq[i]; lk[i] = gk[i]; lv[i] = gv[i]; }
  }
  __syncthreads();

  // S = Q K^T : 6x6 16-tiles, K=64
  for (int p = 0; p < 9; ++p) {
    int pair = wave + p * 4;
    int mt = pair / 6, nt = pair - mt * 6;
    f32x4 acc = {0.f, 0.f, 0.f, 0.f};
#pragma unroll
    for (int kk = 0; kk < 2; ++kk) {
      bf16x8 a  = *(const bf16x8*)(Qs + (mt * 16 + r16) * 64 + kk * 32 + r4 * 8);
      bf16x8 bb = *(const bf16x8*)(Ks + (nt * 16 + r16) * 64 + kk * 32 + r4 * 8);
      acc = __builtin_amdgcn_mfma_f32_16x16x32_bf16(a, bb, acc, 0, 0, 0);
    }
    int row0 = mt * 16 + r4 * 4, col = nt * 16 + r16;
#pragma unroll
    for (int r = 0; r < 4; ++r) Sb[(row0 + r) * 96 + col] = acc[r];
  }
  __syncthreads();

  // masked softmax, one 32-lane group per row
  int group = tid >> 5, glane = tid & 31;
  for (int r = group; r < 96; r += 8) {
    if (r < 87) {
      int lr = mod29(r);
      float sv[3]; bool al[3];
      float mx = -__builtin_inff();
#pragma unroll
      for (int q = 0; q < 3; ++q) {
        int j = glane + q * 32;
        int lj = mod29(j);  // only meaningful for j<87; masked otherwise
        al[q] = (j < 87) && (lj <= lr) && (lj >= lr - 21);
        sv[q] = al[q] ? Sb[r * 96 + j] * 0.125f : -__builtin_inff();
        mx = fmaxf(mx, sv[q]);
      }
#pragma unroll
      for (int o = 16; o >= 1; o >>= 1) mx = fmaxf(mx, __shfl_xor(mx, o, 32));
      float e[3], sum = 0.f;
#pragma unroll
      for (int q = 0; q < 3; ++q) { e[q] = al[q] ? __expf(sv[q] - mx) : 0.f; sum += e[q]; }
#pragma unroll
      for (int o = 16; o >= 1; o >>= 1) sum += __shfl_xor(sum, o, 32);
      float inv = 1.f / sum;
#pragma unroll
      for (int q = 0; q < 3; ++q)
        Pb[r * 96 + glane + q * 32] = __float2bfloat16(e[q] * inv);
    } else {
#pragma unroll
      for (int q = 0; q < 3; ++q) Pb[r * 96 + glane + q * 32] = __float2bfloat16(0.f);
    }
  }
  __syncthreads();

  // Y = P V : A=P [96][96], Bt=Vt [64][96], 6x4 16-tiles, K=96
  for (int p = 0; p < 6; ++p) {
    int pair = wave + p * 4;
    int mt = pair >> 2, nt = pair & 3;
    f32x4 acc = {0.f, 0.f, 0.f, 0.f};
#pragma unroll
    for (int kk = 0; kk < 3; ++kk) {
      bf16x8 a  = *(const bf16x8*)(Pb + (mt * 16 + r16) * 96 + kk * 32 + r4 * 8);
      bf16x8 bb = *(const bf16x8*)(Vts + (nt * 16 + r16) * 96 + kk * 32 + r4 * 8);
      acc = __builtin_amdgcn_mfma_f32_16x16x32_bf16(a, bb, acc, 0, 0, 0);
    }
    int t0 = mt * 16 + r4 * 4, d = nt * 16 + r16;
#pragma unroll
    for (int r = 0; r < 4; ++r) {
      int t = t0 + r;
      if (t < 87)
        y_ws[((size_t)b * 87 + t) * 512 + h * 64 + d] = __float2bfloat16(acc[r]);
    }
  }
}

// ---------------- output projection ----------------
__global__ __launch_bounds__(256) void gemm_proj_kernel(
    const __hip_bfloat16* __restrict__ A, const __hip_bfloat16* __restrict__ Bt,
    const float* __restrict__ bias, float* __restrict__ out) {
  __shared__ __align__(16) __hip_bfloat16 As[128 * 64];
  __shared__ __align__(16) __hip_bfloat16 Bs[128 * 64];
  const int K = 512;
  int tid = threadIdx.x, lane = tid & 63, wave = tid >> 6;
  int tileN = blockIdx.x * 128;
  int tileM = blockIdx.y * 128;
  int wr = wave >> 1, wc = wave & 1;
  int r16 = lane & 15, r4 = lane >> 4;
  int srow = lane >> 3, scol = (lane & 7) * 8;

  f32x4 acc[4][4] = {};

  for (int kt = 0; kt < 8; ++kt) {
    int k0 = kt * 64;
#pragma unroll
    for (int i = 0; i < 4; ++i) {
      int blkr = (i * 4 + wave) * 8;
      const __hip_bfloat16* gA = A + (size_t)(tileM + blkr + srow) * K + k0 + scol;
      const __hip_bfloat16* gB = Bt + (size_t)(tileN + blkr + srow) * K + k0 + scol;
      gl_lds16(gA, (char*)As + blkr * 128);
      gl_lds16(gB, (char*)Bs + blkr * 128);
    }
    __syncthreads();
#pragma unroll
    for (int kk = 0; kk < 2; ++kk) {
      bf16x8 af[4], bf[4];
#pragma unroll
      for (int mi = 0; mi < 4; ++mi)
        af[mi] = *(const bf16x8*)((const char*)As +
                                  (wr * 64 + mi * 16 + r16) * 128 + kk * 64 + r4 * 16);
#pragma unroll
      for (int ni = 0; ni < 4; ++ni)
        bf[ni] = *(const bf16x8*)((const char*)Bs +
                                  (wc * 64 + ni * 16 + r16) * 128 + kk * 64 + r4 * 16);
#pragma unroll
      for (int mi = 0; mi < 4; ++mi)
#pragma unroll
        for (int ni = 0; ni < 4; ++ni)
          acc[mi][ni] = __builtin_amdgcn_mfma_f32_16x16x32_bf16(af[mi], bf[ni],
                                                                acc[mi][ni], 0, 0, 0);
    }
    __syncthreads();
  }

#pragma unroll
  for (int mi = 0; mi < 4; ++mi) {
#pragma unroll
    for (int ni = 0; ni < 4; ++ni) {
      int gn = tileN + wc * 64 + ni * 16 + r16;
      float bv = bias[gn];
#pragma unroll
      for (int r = 0; r < 4; ++r) {
        int gm = tileM + wr * 64 + mi * 16 + r4 * 4 + r;
        out[(size_t)gm * 512 + gn] = acc[mi][ni][r] + bv;
      }
    }
  }
}

// ---------------- launch ----------------
extern "C" void kernel_launch(void* const* d_in, const int* in_sizes, int n_in,
                              void* d_out, int out_size, void* d_ws, size_t ws_size,
                              hipStream_t stream) {
  const float* x  = (const float*)d_in[0];
  const float* Wq = (const float*)d_in[1];
  const float* bq = (const float*)d_in[2];
  const float* Wk = (const float*)d_in[3];
  const float* bk = (const float*)d_in[4];
  const float* Wv = (const float*)d_in[5];
  const float* bv = (const float*)d_in[6];
  const float* Wp = (const float*)d_in[7];
  const float* bp = (const float*)d_in[8];
  float* out = (float*)d_out;

  char* ws = (char*)d_ws;
  size_t off = 0;
  __hip_bfloat16* xb    = (__hip_bfloat16*)(ws + off); off += (size_t)BT_ * 512 * 2;  // 45613056
  __hip_bfloat16* wqkv  = (__hip_bfloat16*)(ws + off); off += 1536 * 512 * 2;
  __hip_bfloat16* wp    = (__hip_bfloat16*)(ws + off); off += 512 * 512 * 2;
  float*          biasc = (float*)(ws + off);          off += 8192;
  __hip_bfloat16* q_ws  = (__hip_bfloat16*)(ws + off); off += (size_t)BH_ * 6144 * 2;
  __hip_bfloat16* k_ws  = (__hip_bfloat16*)(ws + off); off += (size_t)BH_ * 6144 * 2;
  __hip_bfloat16* vt_ws = (__hip_bfloat16*)(ws + off); off += (size_t)BH_ * 6144 * 2;
  __hip_bfloat16* yb = xb;  // alias: xb fully consumed by gemm_qkv before attn writes y

  if (ws_size < off) return;  // workspace too small (signature: all-zero output)

  convert_x_kernel<<<2048, 256, 0, stream>>>(x, xb, BT_ * 512 / 4);
  convert_w_kernel<<<1024, 256, 0, stream>>>(Wq, Wk, Wv, Wp, bq, bk, bv, wqkv, wp, biasc);
  zero_pads_kernel<<<2048, 256, 0, stream>>>(q_ws, k_ws, vt_ws);
  gemm_qkv_kernel<<<dim3(12, 348), 256, 0, stream>>>(xb, wqkv, biasc, q_ws, k_ws, vt_ws);
  attn_kernel<<<BH_, 256, 0, stream>>>(q_ws, k_ws, vt_ws, yb);
  gemm_proj_kernel<<<dim3(4, 348), 256, 0, stream>>>(yb, wp, bp, out);
}

// Round 2
// 337.933 us; speedup vs baseline: 1.0637x; 1.0637x over previous
//
#include <hip/hip_runtime.h>
#include <hip/hip_bf16.h>
#include <stdint.h>

// Problem constants
#define B_   512
#define T_   87
#define C_   512
#define H_   8
#define D_   64
#define BT_  44544        // B_*T_
#define BH_  4096         // B_*H_

typedef __attribute__((ext_vector_type(4))) float f32x4;
typedef __attribute__((ext_vector_type(8))) __bf16 bf16x8;
typedef __attribute__((ext_vector_type(4))) unsigned short u16x4;

__device__ __forceinline__ void gl_lds16(const void* g, void* l) {
  __builtin_amdgcn_global_load_lds(
      (const __attribute__((address_space(1))) unsigned int*)g,
      (__attribute__((address_space(3))) unsigned int*)l, 16, 0, 0);
}

__device__ __forceinline__ int mod29(int x) {
  return x < 29 ? x : (x < 58 ? x - 29 : x - 58);
}

// ---------------- converts ----------------

__global__ void convert_x_kernel(const float* __restrict__ x,
                                 __hip_bfloat16* __restrict__ xb, int n4) {
  int stride = gridDim.x * blockDim.x;
  for (int i = blockIdx.x * blockDim.x + threadIdx.x; i < n4; i += stride) {
    f32x4 v = ((const f32x4*)x)[i];
    u16x4 o;
    o.x = __builtin_bit_cast(unsigned short, __float2bfloat16(v.x));
    o.y = __builtin_bit_cast(unsigned short, __float2bfloat16(v.y));
    o.z = __builtin_bit_cast(unsigned short, __float2bfloat16(v.z));
    o.w = __builtin_bit_cast(unsigned short, __float2bfloat16(v.w));
    ((u16x4*)xb)[i] = o;
  }
}

__global__ void convert_w_kernel(const float* __restrict__ Wq, const float* __restrict__ Wk,
                                 const float* __restrict__ Wv, const float* __restrict__ Wp,
                                 const float* __restrict__ bq, const float* __restrict__ bk,
                                 const float* __restrict__ bv,
                                 __hip_bfloat16* __restrict__ wqkv,
                                 __hip_bfloat16* __restrict__ wp,
                                 float* __restrict__ biasc) {
  const int NW = 262144;                 // 512*512
  const int total = 3 * NW + NW + 1536;
  int stride = gridDim.x * blockDim.x;
  for (int i = blockIdx.x * blockDim.x + threadIdx.x; i < total; i += stride) {
    if (i < 3 * NW) {
      float v = (i < NW) ? Wq[i] : (i < 2 * NW ? Wk[i - NW] : Wv[i - 2 * NW]);
      wqkv[i] = __float2bfloat16(v);
    } else if (i < 4 * NW) {
      wp[i - 3 * NW] = __float2bfloat16(Wp[i - 3 * NW]);
    } else {
      int j = i - 4 * NW;
      biasc[j] = (j < 512) ? bq[j] : (j < 1024 ? bk[j - 512] : bv[j - 1024]);
    }
  }
}

// zero the pad rows (t = 87..95) of q/k and pad cols of vt
__global__ void zero_pads_kernel(__hip_bfloat16* __restrict__ q_ws,
                                 __hip_bfloat16* __restrict__ k_ws,
                                 __hip_bfloat16* __restrict__ vt_ws) {
  const int per = BH_ * 576;  // 9*64 pad elems per (b,h)
  int stride = gridDim.x * blockDim.x;
  __hip_bfloat16 z = __float2bfloat16(0.f);
  for (int i = blockIdx.x * blockDim.x + threadIdx.x; i < 3 * per; i += stride) {
    if (i < per) {
      int bh = i / 576, rem = i - (i / 576) * 576;
      q_ws[(size_t)bh * 6144 + 5568 + rem] = z;
    } else if (i < 2 * per) {
      int j = i - per;
      int bh = j / 576, rem = j - (j / 576) * 576;
      k_ws[(size_t)bh * 6144 + 5568 + rem] = z;
    } else {
      int j = i - 2 * per;
      int bh = j / 576, rem = j - (j / 576) * 576;
      int d = rem / 9, o = rem - d * 9;
      vt_ws[(size_t)bh * 6144 + d * 96 + 87 + o] = z;
    }
  }
}

// ---------------- shared GEMM building blocks ----------------
// LDS tile: ROWS rows x 64 bf16 (128B rows), linear, but holding the
// XOR-swizzled layout: LDS 16B-slot s of row r contains global slot s^(r&7).
// Achieved by pre-swizzling the per-lane GLOBAL column (m173 pattern), since
// global_load_lds writes linearly (wave-uniform base + lane*16).
template<int ROWS, int NW>
__device__ __forceinline__ void stage_tile(const char* g, size_t ldb, int kbyte,
                                           char* lbuf, int wave, int lane) {
  const int colsw = ((lane & 7) ^ (lane >> 3)) * 16;  // source slot = s ^ (row&7)
  const int rl = lane >> 3;
#pragma unroll
  for (int j = 0; j < ROWS / (NW * 8); ++j) {
    int rbase = j * NW * 8 + wave * 8;                 // wave-uniform
    const char* src = g + (size_t)(rbase + rl) * ldb + kbyte + colsw;
    gl_lds16(src, lbuf + rbase * 128);
  }
}

// compute one BK=64 K-tile: acc[FM][FN] += A[wbM..][k] * B[wbN..][k]^T
template<int FM, int FN>
__device__ __forceinline__ void compute_tile(const char* Ab, const char* Bb,
                                             int wbM, int wbN, int r16, int r4,
                                             f32x4 acc[FM][FN]) {
  const int cxor = (r16 & 7) << 4;   // row&7 == r16&7 (bases are multiples of 16)
  bf16x8 bf[FN][2];
#pragma unroll
  for (int fn = 0; fn < FN; ++fn) {
    int row = wbN + fn * 16 + r16;
#pragma unroll
    for (int kk = 0; kk < 2; ++kk)
      bf[fn][kk] = *(const bf16x8*)(Bb + row * 128 + ((kk * 64 + r4 * 16) ^ cxor));
  }
#pragma unroll
  for (int fm = 0; fm < FM; ++fm) {
    int row = wbM + fm * 16 + r16;
    bf16x8 a0 = *(const bf16x8*)(Ab + row * 128 + ((r4 * 16) ^ cxor));
    bf16x8 a1 = *(const bf16x8*)(Ab + row * 128 + ((64 + r4 * 16) ^ cxor));
#pragma unroll
    for (int fn = 0; fn < FN; ++fn) {
      acc[fm][fn] = __builtin_amdgcn_mfma_f32_16x16x32_bf16(a0, bf[fn][0], acc[fm][fn], 0, 0, 0);
      acc[fm][fn] = __builtin_amdgcn_mfma_f32_16x16x32_bf16(a1, bf[fn][1], acc[fm][fn], 0, 0, 0);
    }
  }
}

// ---------------- fused QKV GEMM: 256x256 tile, BK=64, 8 waves, 2-phase dbuf ----
// A: xb [44544,512] bf16; Bt: wqkv [1536,512] bf16 (y = x @ W^T)
__global__ __launch_bounds__(512, 2) void gemm_qkv_kernel(
    const __hip_bfloat16* __restrict__ A, const __hip_bfloat16* __restrict__ Bt,
    const float* __restrict__ bias,
    __hip_bfloat16* __restrict__ q_ws, __hip_bfloat16* __restrict__ k_ws,
    __hip_bfloat16* __restrict__ vt_ws) {
  __shared__ __align__(16) char smem[131072];  // 2 x (A 32KB + B 32KB)
  int tid = threadIdx.x, lane = tid & 63, wave = tid >> 6;
  int r16 = lane & 15, r4 = lane >> 4;

  // bijective XCD swizzle (m204): nwg = 1044 = 6(N) x 174(M)
  int orig = blockIdx.x;
  int xcd = orig & 7, idx = orig >> 3;
  const int q8 = 130, r8 = 4;  // 1044 = 8*130 + 4
  int wg = (xcd < r8 ? xcd * (q8 + 1) : r8 * (q8 + 1) + (xcd - r8) * q8) + idx;
  int tileM = (wg / 6) * 256, tileN = (wg % 6) * 256;

  int wr = wave >> 2, wc = wave & 3;   // 2 M-waves x 4 N-waves; per-wave 128x64

  f32x4 acc[8][4] = {};

  const char* Ag = (const char*)A + (size_t)tileM * 1024;   // row stride 1024B
  const char* Bg = (const char*)Bt + (size_t)tileN * 1024;

  // prologue: stage K-tile 0 into buffer 0
  stage_tile<256, 8>(Ag, 1024, 0, smem, wave, lane);
  stage_tile<256, 8>(Bg, 1024, 0, smem + 32768, wave, lane);
  __syncthreads();

  for (int kt = 0; kt < 8; ++kt) {
    char* cur = smem + (kt & 1) * 65536;
    if (kt < 7) {   // issue next-tile loads BEFORE computing current (T3 2-phase)
      char* nxt = smem + ((kt + 1) & 1) * 65536;
      stage_tile<256, 8>(Ag, 1024, (kt + 1) * 128, nxt, wave, lane);
      stage_tile<256, 8>(Bg, 1024, (kt + 1) * 128, nxt + 32768, wave, lane);
    }
    __builtin_amdgcn_s_setprio(1);
    compute_tile<8, 4>(cur, cur + 32768, wr * 128, wc * 64, r16, r4, acc);
    __builtin_amdgcn_s_setprio(0);
    __syncthreads();   // drains vmcnt (next tile landed) + lgkm, barrier
  }

  // epilogue: C/D layout col=lane&15, row=(lane>>4)*4+reg [m89-verified]
#pragma unroll
  for (int fm = 0; fm < 8; ++fm) {
    int gmb = tileM + wr * 128 + fm * 16 + r4 * 4;
#pragma unroll
    for (int fn = 0; fn < 4; ++fn) {
      int gn = tileN + wc * 64 + fn * 16 + r16;
      float bv = bias[gn];
      int sel = gn >> 9;          // 0=q, 1=k, 2=v
      int n2 = gn & 511;
      int hh = n2 >> 6, dd = n2 & 63;
#pragma unroll
      for (int rr = 0; rr < 4; ++rr) {
        int gm = gmb + rr;
        int bb = gm / 87, tt = gm - bb * 87;
        __hip_bfloat16 hv = __float2bfloat16(acc[fm][fn][rr] + bv);
        if (sel == 0)
          q_ws[((size_t)(bb * 8 + hh) * 96 + tt) * 64 + dd] = hv;
        else if (sel == 1)
          k_ws[((size_t)(bb * 8 + hh) * 96 + tt) * 64 + dd] = hv;
        else
          vt_ws[((size_t)(bb * 8 + hh) * 64 + dd) * 96 + tt] = hv;
      }
    }
  }
}

// ---------------- attention per (b,h) (unchanged this round) ----------------
__global__ __launch_bounds__(256) void attn_kernel(
    const __hip_bfloat16* __restrict__ q_ws, const __hip_bfloat16* __restrict__ k_ws,
    const __hip_bfloat16* __restrict__ vt_ws, __hip_bfloat16* __restrict__ y_ws) {
  __shared__ __align__(16) char smem[73728];
  __hip_bfloat16* Qs  = (__hip_bfloat16*)smem;             // [96][64] 12KB
  __hip_bfloat16* Ks  = (__hip_bfloat16*)(smem + 12288);   // [96][64] 12KB
  __hip_bfloat16* Vts = (__hip_bfloat16*)(smem + 24576);   // [64][96] 12KB
  float* Sb           = (float*)(smem + 36864);            // [96][96] fp32 36KB
  __hip_bfloat16* Pb  = (__hip_bfloat16*)smem;             // [96][96] aliases Qs+Ks

  int tid = threadIdx.x, lane = tid & 63, wave = tid >> 6;
  int bh = blockIdx.x, b = bh >> 3, h = bh & 7;
  int r16 = lane & 15, r4 = lane >> 4;

  {
    const bf16x8* gq = (const bf16x8*)(q_ws + (size_t)bh * 6144);
    const bf16x8* gk = (const bf16x8*)(k_ws + (size_t)bh * 6144);
    const bf16x8* gv = (const bf16x8*)(vt_ws + (size_t)bh * 6144);
    bf16x8* lq = (bf16x8*)Qs; bf16x8* lk = (bf16x8*)Ks; bf16x8* lv = (bf16x8*)Vts;
    for (int i = tid; i < 768; i += 256) { lq[i] = gq[i]; lk[i] = gk[i]; lv[i] = gv[i]; }
  }
  __syncthreads();

  // S = Q K^T : 6x6 16-tiles, K=64
  for (int p = 0; p < 9; ++p) {
    int pair = wave + p * 4;
    int mt = pair / 6, nt = pair - mt * 6;
    f32x4 acc = {0.f, 0.f, 0.f, 0.f};
#pragma unroll
    for (int kk = 0; kk < 2; ++kk) {
      bf16x8 a  = *(const bf16x8*)(Qs + (mt * 16 + r16) * 64 + kk * 32 + r4 * 8);
      bf16x8 bb = *(const bf16x8*)(Ks + (nt * 16 + r16) * 64 + kk * 32 + r4 * 8);
      acc = __builtin_amdgcn_mfma_f32_16x16x32_bf16(a, bb, acc, 0, 0, 0);
    }
    int row0 = mt * 16 + r4 * 4, col = nt * 16 + r16;
#pragma unroll
    for (int r = 0; r < 4; ++r) Sb[(row0 + r) * 96 + col] = acc[r];
  }
  __syncthreads();

  // masked softmax, one 32-lane group per row
  int group = tid >> 5, glane = tid & 31;
  for (int r = group; r < 96; r += 8) {
    if (r < 87) {
      int lr = mod29(r);
      float sv[3]; bool al[3];
      float mx = -__builtin_inff();
#pragma unroll
      for (int q = 0; q < 3; ++q) {
        int j = glane + q * 32;
        int lj = mod29(j);
        al[q] = (j < 87) && (lj <= lr) && (lj >= lr - 21);
        sv[q] = al[q] ? Sb[r * 96 + j] * 0.125f : -__builtin_inff();
        mx = fmaxf(mx, sv[q]);
      }
#pragma unroll
      for (int o = 16; o >= 1; o >>= 1) mx = fmaxf(mx, __shfl_xor(mx, o, 32));
      float e[3], sum = 0.f;
#pragma unroll
      for (int q = 0; q < 3; ++q) { e[q] = al[q] ? __expf(sv[q] - mx) : 0.f; sum += e[q]; }
#pragma unroll
      for (int o = 16; o >= 1; o >>= 1) sum += __shfl_xor(sum, o, 32);
      float inv = 1.f / sum;
#pragma unroll
      for (int q = 0; q < 3; ++q)
        Pb[r * 96 + glane + q * 32] = __float2bfloat16(e[q] * inv);
    } else {
#pragma unroll
      for (int q = 0; q < 3; ++q) Pb[r * 96 + glane + q * 32] = __float2bfloat16(0.f);
    }
  }
  __syncthreads();

  // Y = P V : A=P [96][96], Bt=Vt [64][96], 6x4 16-tiles, K=96
  for (int p = 0; p < 6; ++p) {
    int pair = wave + p * 4;
    int mt = pair >> 2, nt = pair & 3;
    f32x4 acc = {0.f, 0.f, 0.f, 0.f};
#pragma unroll
    for (int kk = 0; kk < 3; ++kk) {
      bf16x8 a  = *(const bf16x8*)(Pb + (mt * 16 + r16) * 96 + kk * 32 + r4 * 8);
      bf16x8 bb = *(const bf16x8*)(Vts + (nt * 16 + r16) * 96 + kk * 32 + r4 * 8);
      acc = __builtin_amdgcn_mfma_f32_16x16x32_bf16(a, bb, acc, 0, 0, 0);
    }
    int t0 = mt * 16 + r4 * 4, d = nt * 16 + r16;
#pragma unroll
    for (int r = 0; r < 4; ++r) {
      int t = t0 + r;
      if (t < 87)
        y_ws[((size_t)b * 87 + t) * 512 + h * 64 + d] = __float2bfloat16(acc[r]);
    }
  }
}

// ---------------- output projection: 128x128 tile, BK=64, 4 waves, 2-phase ----
__global__ __launch_bounds__(256, 4) void gemm_proj_kernel(
    const __hip_bfloat16* __restrict__ A, const __hip_bfloat16* __restrict__ Bt,
    const float* __restrict__ bias, float* __restrict__ out) {
  __shared__ __align__(16) char smem[65536];  // 2 x (A 16KB + B 16KB)
  int tid = threadIdx.x, lane = tid & 63, wave = tid >> 6;
  int r16 = lane & 15, r4 = lane >> 4;

  // XCD swizzle: nwg = 1392 = 4(N) x 348(M), divisible by 8
  int orig = blockIdx.x;
  int wg = (orig & 7) * 174 + (orig >> 3);
  int tileM = (wg >> 2) * 128, tileN = (wg & 3) * 128;

  int wr = wave >> 1, wc = wave & 1;   // per-wave 64x64

  f32x4 acc[4][4] = {};

  const char* Ag = (const char*)A + (size_t)tileM * 1024;
  const char* Bg = (const char*)Bt + (size_t)tileN * 1024;

  stage_tile<128, 4>(Ag, 1024, 0, smem, wave, lane);
  stage_tile<128, 4>(Bg, 1024, 0, smem + 16384, wave, lane);
  __syncthreads();

  for (int kt = 0; kt < 8; ++kt) {
    char* cur = smem + (kt & 1) * 32768;
    if (kt < 7) {
      char* nxt = smem + ((kt + 1) & 1) * 32768;
      stage_tile<128, 4>(Ag, 1024, (kt + 1) * 128, nxt, wave, lane);
      stage_tile<128, 4>(Bg, 1024, (kt + 1) * 128, nxt + 16384, wave, lane);
    }
    __builtin_amdgcn_s_setprio(1);
    compute_tile<4, 4>(cur, cur + 16384, wr * 64, wc * 64, r16, r4, acc);
    __builtin_amdgcn_s_setprio(0);
    __syncthreads();
  }

#pragma unroll
  for (int fm = 0; fm < 4; ++fm) {
    int gmb = tileM + wr * 64 + fm * 16 + r4 * 4;
#pragma unroll
    for (int fn = 0; fn < 4; ++fn) {
      int gn = tileN + wc * 64 + fn * 16 + r16;
      float bv = bias[gn];
#pragma unroll
      for (int rr = 0; rr < 4; ++rr)
        out[(size_t)(gmb + rr) * 512 + gn] = acc[fm][fn][rr] + bv;
    }
  }
}

// ---------------- launch ----------------
extern "C" void kernel_launch(void* const* d_in, const int* in_sizes, int n_in,
                              void* d_out, int out_size, void* d_ws, size_t ws_size,
                              hipStream_t stream) {
  const float* x  = (const float*)d_in[0];
  const float* Wq = (const float*)d_in[1];
  const float* bq = (const float*)d_in[2];
  const float* Wk = (const float*)d_in[3];
  const float* bk = (const float*)d_in[4];
  const float* Wv = (const float*)d_in[5];
  const float* bv = (const float*)d_in[6];
  const float* Wp = (const float*)d_in[7];
  const float* bp = (const float*)d_in[8];
  float* out = (float*)d_out;

  char* ws = (char*)d_ws;
  size_t off = 0;
  __hip_bfloat16* xb    = (__hip_bfloat16*)(ws + off); off += (size_t)BT_ * 512 * 2;
  __hip_bfloat16* wqkv  = (__hip_bfloat16*)(ws + off); off += 1536 * 512 * 2;
  __hip_bfloat16* wp    = (__hip_bfloat16*)(ws + off); off += 512 * 512 * 2;
  float*          biasc = (float*)(ws + off);          off += 8192;
  __hip_bfloat16* q_ws  = (__hip_bfloat16*)(ws + off); off += (size_t)BH_ * 6144 * 2;
  __hip_bfloat16* k_ws  = (__hip_bfloat16*)(ws + off); off += (size_t)BH_ * 6144 * 2;
  __hip_bfloat16* vt_ws = (__hip_bfloat16*)(ws + off); off += (size_t)BH_ * 6144 * 2;
  __hip_bfloat16* yb = xb;  // alias: xb fully consumed by gemm_qkv before attn writes y

  if (ws_size < off) return;

  convert_x_kernel<<<2048, 256, 0, stream>>>(x, xb, BT_ * 512 / 4);
  convert_w_kernel<<<1024, 256, 0, stream>>>(Wq, Wk, Wv, Wp, bq, bk, bv, wqkv, wp, biasc);
  zero_pads_kernel<<<2048, 256, 0, stream>>>(q_ws, k_ws, vt_ws);
  gemm_qkv_kernel<<<1044, 512, 0, stream>>>(xb, wqkv, biasc, q_ws, k_ws, vt_ws);
  attn_kernel<<<BH_, 256, 0, stream>>>(q_ws, k_ws, vt_ws, yb);
  gemm_proj_kernel<<<1392, 256, 0, stream>>>(yb, wp, bp, out);
}